// Round 8
// baseline (160.339 us; speedup 1.0000x reference)
//
#include <hip/hip_runtime.h>

typedef short bf16x8 __attribute__((ext_vector_type(8)));
typedef float f32x16 __attribute__((ext_vector_type(16)));

#define DI __device__ __forceinline__

constexpr int BS = 2, CH = 128;
constexpr int NQ = 16384, NM = 4096;
constexpr size_t NX = (size_t)BS * CH * NQ;   // elements per output tensor

DI float bf2f(ushort u) { unsigned v = ((unsigned)u) << 16; return __builtin_bit_cast(float, v); }
DI ushort f2bf(float f) {
  unsigned u = __builtin_bit_cast(unsigned, f);
  u += 0x7FFFu + ((u >> 16) & 1u);   // RNE
  return (ushort)(u >> 16);
}
DI float ldany(const void* p, size_t i, int f) {
  return f ? ((const float*)p)[i] : bf2f(((const ushort*)p)[i]);
}
DI f32x16 mfma_bf16(bf16x8 a, bf16x8 b, f32x16 c) {
  return __builtin_amdgcn_mfma_f32_32x32x16_bf16(a, b, c, 0, 0, 0);
}
DI float fexp2(float x) { return __builtin_amdgcn_exp2f(x); }   // 1x v_exp_f32

// ---------------- dtype sniff ----------------
__global__ void k_sniff(const void* __restrict__ x, int* __restrict__ flag) {
  if (threadIdx.x == 0 && blockIdx.x == 0) {
    const ushort* u = (const ushort*)x;
    int garbage = 0, zeros = 0;
    for (int i = 0; i < 256; ++i) {
      float v = bf2f(u[i]);
      if (!(fabsf(v) < 1e9f)) garbage++;
      if ((i & 1) == 0 && u[i] == 0) zeros++;
    }
    flag[0] = (garbage >= 8 || zeros >= 100) ? 1 : 0;   // 1 = f32 buffers
  }
}

// ---------------- canonicalize x to bf16 (f32 mode only) ----------------
__global__ __launch_bounds__(256) void k_convert(
    const void* __restrict__ x, const int* __restrict__ flag, ushort* __restrict__ xc)
{
  if (!flag[0]) return;
  size_t i = ((size_t)blockIdx.x * 256 + threadIdx.x) * 8;
  const float* xf = (const float*)x;
  union { uint4 v4; ushort s[8]; } o;
  #pragma unroll
  for (int k = 0; k < 8; ++k) o.s[k] = f2bf(xf[i + k]);
  *(uint4*)(xc + i) = o.v4;
}

// ---------------- weight prep ----------------
__global__ __launch_bounds__(256) void k_prep(
    const void* __restrict__ wT, const void* __restrict__ bT,
    const void* __restrict__ wP, const void* __restrict__ bP,
    const void* __restrict__ wG, const void* __restrict__ bG,
    const void* __restrict__ wAG, const void* __restrict__ bAG,
    const int* __restrict__ flag,
    float* __restrict__ wAllf, float* __restrict__ bAllf, uint4* __restrict__ wF)
{
  int t = threadIdx.x;
  int f = flag[0];
  if (blockIdx.x == 0) {
    for (int i = t; i < 16 * 128; i += 256) wAllf[i]        = ldany(wT, i, f);
    for (int i = t; i < 16 * 128; i += 256) wAllf[2048 + i] = ldany(wP, i, f);
    for (int i = t; i < 64 * 128; i += 256) wAllf[4096 + i] = ldany(wG, i, f);
    if (t < 16)  bAllf[t]       = ldany(bT, t, f);
    if (t < 16)  bAllf[16 + t]  = ldany(bP, t, f);
    if (t < 64)  bAllf[32 + t]  = ldany(bG, t, f);
    if (t < 128) bAllf[96 + t]  = ldany(bAG, t, f);
  } else {
    int idx = (blockIdx.x - 1) * 256 + t;  // 0..1023
    int lane = idx & 63, ks = (idx >> 6) & 3, ot = idx >> 8;
    size_t src = (size_t)(ot * 32 + (lane & 31)) * 64 + ks * 16 + (lane >> 5) * 8;
    union { uint4 v4; ushort s[8]; } o;
    #pragma unroll
    for (int j = 0; j < 8; ++j) o.s[j] = f2bf(ldany(wAG, src + j, f));
    wF[idx] = o.v4;
  }
}

// ---------------- projections ----------------
// 3 channel-groups of 32 outputs (halves x re-reads vs 6 groups), 1 q/thread.
// grp 0: theta[0..16) (tanh*log2e) + phi[16..32) (pool,tanh)
// grp 1: g[0..32), grp 2: g[32..64)  (pool, row-major gm[m][64] bf16)
__global__ __launch_bounds__(256) void k_proj(
    const void* __restrict__ x, const ushort* __restrict__ xc,
    const int* __restrict__ flag,
    const float* __restrict__ wAllf, const float* __restrict__ bAllf,
    ushort* __restrict__ theta, ushort* __restrict__ phi, ushort* __restrict__ gm)
{
  int b = blockIdx.y;
  int grp = blockIdx.x >> 6, qt = blockIdx.x & 63;
  int t = threadIdx.x, lane = t & 63;
  int q = qt * 256 + t;
  int f = flag[0];
  const float* wp = wAllf + grp * 4096;   // 32 rows x 128

  const ushort* xb = (f ? xc : (const ushort*)x) + (size_t)b * CH * NQ + q;

  float acc[32];
  #pragma unroll
  for (int o = 0; o < 32; ++o) acc[o] = 0.f;

  for (int c0 = 0; c0 < CH; c0 += 8) {
    float xv[8];
    #pragma unroll
    for (int k = 0; k < 8; ++k) xv[k] = bf2f(xb[(size_t)(c0 + k) * NQ]);
    #pragma unroll
    for (int o = 0; o < 32; ++o) {
      #pragma unroll
      for (int k = 0; k < 8; ++k) acc[o] = fmaf(xv[k], wp[o * 128 + c0 + k], acc[o]);
    }
  }

  constexpr float L2E = 1.4426950408889634f;

  if (grp == 0) {
    union { uint4 v4[2]; ushort s[16]; } th;
    #pragma unroll
    for (int o = 0; o < 16; ++o) th.s[o] = f2bf(tanhf(acc[o] + bAllf[o]) * L2E);
    uint4* dst = (uint4*)(theta + ((size_t)b * NQ + q) * 16);
    dst[0] = th.v4[0]; dst[1] = th.v4[1];

    float z[16];
    #pragma unroll
    for (int o = 0; o < 16; ++o) {
      float m2 = acc[16 + o] + bAllf[16 + o];
      m2 = fmaxf(m2, __shfl_xor(m2, 1, 64));    // h-pair
      z[o] = fmaxf(m2, __shfl_xor(m2, 32, 64)); // w-pair
    }
    if ((lane & 1) == 0 && (lane & 32) == 0) {
      int hh = q & 31, ww = (q >> 5) & 31, nn = q >> 10;
      int m = nn * 256 + (ww >> 1) * 16 + (hh >> 1);
      union { uint4 v4[2]; ushort s[16]; } ph;
      #pragma unroll
      for (int o = 0; o < 16; ++o) ph.s[o] = f2bf(tanhf(z[o]));
      uint4* pdst = (uint4*)(phi + ((size_t)b * NM + m) * 16);
      pdst[0] = ph.v4[0]; pdst[1] = ph.v4[1];
    }
  } else {
    int c0 = (grp - 1) * 32;
    float z[32];
    #pragma unroll
    for (int o = 0; o < 32; ++o) {
      float m2 = acc[o] + bAllf[32 + c0 + o];
      m2 = fmaxf(m2, __shfl_xor(m2, 1, 64));
      z[o] = fmaxf(m2, __shfl_xor(m2, 32, 64));
    }
    if ((lane & 1) == 0 && (lane & 32) == 0) {
      int hh = q & 31, ww = (q >> 5) & 31, nn = q >> 10;
      int m = nn * 256 + (ww >> 1) * 16 + (hh >> 1);
      union { uint4 v4[4]; ushort s[32]; } gv;
      #pragma unroll
      for (int o = 0; o < 32; ++o) gv.s[o] = f2bf(z[o]);
      uint4* gdst = (uint4*)(gm + ((size_t)b * NM + m) * 64 + c0);
      gdst[0] = gv.v4[0]; gdst[1] = gv.v4[1]; gdst[2] = gv.v4[2]; gdst[3] = gv.v4[3];
    }
  }
}

// ---------------- softmax denominator partials ----------------
__global__ __launch_bounds__(256, 8) void k_denom(
    const ushort* __restrict__ theta, const ushort* __restrict__ phi,
    float* __restrict__ partial)
{
  int b = blockIdx.z, qs = blockIdx.y;
  int w = threadIdx.x >> 6;
  int l = threadIdx.x & 63, lr = l & 31, lh = l >> 5;
  int m0 = blockIdx.x * 128 + w * 32;

  bf16x8 pB = __builtin_bit_cast(bf16x8, *(const uint4*)(phi + ((size_t)b * NM + m0 + lr) * 16 + lh * 8));

  float s = 0.f;
  int qb = qs * 512;
  for (int qq = 0; qq < 512; qq += 32) {
    bf16x8 tA = __builtin_bit_cast(bf16x8, *(const uint4*)(theta + ((size_t)b * NQ + qb + qq + lr) * 16 + lh * 8));
    f32x16 S;
    #pragma unroll
    for (int i = 0; i < 16; ++i) S[i] = 0.f;
    S = mfma_bf16(tA, pB, S);
    #pragma unroll
    for (int r = 0; r < 16; ++r) s += fexp2(S[r]);
  }
  s += __shfl_xor(s, 32, 64);
  if (l < 32) partial[(((size_t)b * 32 + qs) << 12) + m0 + lr] = s;
}

// ---------------- dinv reduce + scale + PV B-frag pack ----------------
__global__ __launch_bounds__(256) void k_gsf(
    const float* __restrict__ partial, const ushort* __restrict__ gm,
    uint4* __restrict__ gsF)
{
  int b = blockIdx.y, mb = blockIdx.x;   // 128 chunks of 32 m
  int t = threadIdx.x;
  int mbase = mb * 32;

  __shared__ float dinv_sh[32];
  __shared__ float tile[32][65];

  if (t < 32) {
    int m = mbase + t;
    float s = 0.f;
    #pragma unroll
    for (int p = 0; p < 32; ++p) s += partial[(((size_t)b * 32 + p) << 12) + m];
    dinv_sh[t] = 1.f / s;
  }
  __syncthreads();

  {
    int m_loc = t >> 3, c = (t & 7) * 8;
    union { uint4 v4; ushort s[8]; } v;
    v.v4 = *(const uint4*)(gm + ((size_t)b * NM + mbase + m_loc) * 64 + c);
    float dv = dinv_sh[m_loc];
    #pragma unroll
    for (int j = 0; j < 8; ++j) tile[m_loc][c + j] = bf2f(v.s[j]) * dv;
  }
  __syncthreads();

  int ms_loc = t >> 7, ct = (t >> 6) & 1, lane = t & 63;
  int col = ct * 32 + (lane & 31);
  int rbase = ms_loc * 16 + (lane >> 5) * 8;
  union { uint4 v4; ushort s[8]; } o;
  #pragma unroll
  for (int j = 0; j < 8; ++j) o.s[j] = f2bf(tile[rbase + j][col]);
  int ms = (mbase >> 4) + ms_loc;
  gsF[(((size_t)b * 256 + ms) * 2 + ct) * 64 + lane] = o.v4;
}

// ---------------- fused attention + output ----------------
// 1024 threads = 16 waves = (qh 2) x (mq 8); 64 q/block; 16 m-iters/wave.
// Prefetch loads issued at iter TOP (counted-vmcnt pattern: next-iter loads
// stay in flight across this iter's exp/pack/PV). exp2 via v_exp_f32 builtin.
__global__ __launch_bounds__(1024, 4) void k_attn(
    const ushort* __restrict__ theta, const ushort* __restrict__ phi,
    const uint4* __restrict__ gsF, const uint4* __restrict__ wF,
    const float* __restrict__ bAllf, const void* __restrict__ x,
    const void* __restrict__ gamma, const int* __restrict__ flag,
    void* __restrict__ out_base)
{
  int b = blockIdx.y;
  int q0 = blockIdx.x * 64;
  int t = threadIdx.x;
  int w = t >> 6, l = t & 63, lr = l & 31, lh = l >> 5;
  int mq = w & 7, qh = w >> 3;

  __shared__ float agPart[8][32][65];
  __shared__ __align__(16) ushort agF[32][80];

  int qw = q0 + qh * 32;
  bf16x8 tB = __builtin_bit_cast(bf16x8, *(const uint4*)(theta + ((size_t)b * NQ + qw + lr) * 16 + lh * 8));

  const ushort* phb = phi + ((size_t)b * NM + lr) * 16 + lh * 8;
  const uint4* gF = gsF + (size_t)b * 256 * 128;   // per-ms stride = 128 uint4

  f32x16 acc0, acc1;
  #pragma unroll
  for (int i = 0; i < 16; ++i) { acc0[i] = 0.f; acc1[i] = 0.f; }

  int m0 = mq * 32;
  int ms0 = m0 >> 4;
  bf16x8 pA = __builtin_bit_cast(bf16x8, *(const uint4*)(phb + (size_t)m0 * 16));
  uint4 g00 = gF[ms0 * 128 + l];
  uint4 g01 = gF[ms0 * 128 + 64 + l];
  uint4 g10 = gF[ms0 * 128 + 128 + l];
  uint4 g11 = gF[ms0 * 128 + 192 + l];

  for (int it = 0; it < 16; ++it) {
    // issue next-iter loads FIRST (wrap on last iter; values unused)
    int mn = mq * 32 + ((it + 1) & 15) * 256;
    int msn = mn >> 4;
    bf16x8 pAn = __builtin_bit_cast(bf16x8, *(const uint4*)(phb + (size_t)mn * 16));
    uint4 n00 = gF[msn * 128 + l];
    uint4 n01 = gF[msn * 128 + 64 + l];
    uint4 n10 = gF[msn * 128 + 128 + l];
    uint4 n11 = gF[msn * 128 + 192 + l];
    __builtin_amdgcn_sched_barrier(0);   // pin issue point

    f32x16 S;
    #pragma unroll
    for (int i = 0; i < 16; ++i) S[i] = 0.f;
    S = mfma_bf16(pA, tB, S);   // S^T[m][q] (theta pre-scaled by log2e)

    #pragma unroll
    for (int r = 0; r < 16; ++r) S[r] = fexp2(S[r]);   // unnormalized P

    uint u0, u1, u2, u3, u4, u5, u6, u7;
    asm("v_cvt_pk_bf16_f32 %0, %1, %2" : "=v"(u0) : "v"(S[0]),  "v"(S[1]));
    asm("v_cvt_pk_bf16_f32 %0, %1, %2" : "=v"(u1) : "v"(S[2]),  "v"(S[3]));
    asm("v_cvt_pk_bf16_f32 %0, %1, %2" : "=v"(u2) : "v"(S[4]),  "v"(S[5]));
    asm("v_cvt_pk_bf16_f32 %0, %1, %2" : "=v"(u3) : "v"(S[6]),  "v"(S[7]));
    asm("v_cvt_pk_bf16_f32 %0, %1, %2" : "=v"(u4) : "v"(S[8]),  "v"(S[9]));
    asm("v_cvt_pk_bf16_f32 %0, %1, %2" : "=v"(u5) : "v"(S[10]), "v"(S[11]));
    asm("v_cvt_pk_bf16_f32 %0, %1, %2" : "=v"(u6) : "v"(S[12]), "v"(S[13]));
    asm("v_cvt_pk_bf16_f32 %0, %1, %2" : "=v"(u7) : "v"(S[14]), "v"(S[15]));

    asm("v_permlane32_swap_b32 %0, %1" : "+v"(u0), "+v"(u2));
    asm("v_permlane32_swap_b32 %0, %1" : "+v"(u1), "+v"(u3));
    asm("v_permlane32_swap_b32 %0, %1" : "+v"(u4), "+v"(u6));
    asm("v_permlane32_swap_b32 %0, %1" : "+v"(u5), "+v"(u7));

    uint4 fa0 = make_uint4(u0, u1, u2, u3);
    uint4 fa1 = make_uint4(u4, u5, u6, u7);

    acc0 = mfma_bf16(__builtin_bit_cast(bf16x8, fa0), __builtin_bit_cast(bf16x8, g00), acc0);
    acc1 = mfma_bf16(__builtin_bit_cast(bf16x8, fa0), __builtin_bit_cast(bf16x8, g01), acc1);
    acc0 = mfma_bf16(__builtin_bit_cast(bf16x8, fa1), __builtin_bit_cast(bf16x8, g10), acc0);
    acc1 = mfma_bf16(__builtin_bit_cast(bf16x8, fa1), __builtin_bit_cast(bf16x8, g11), acc1);

    pA = pAn; g00 = n00; g01 = n01; g10 = n10; g11 = n11;
  }

  int mode = flag[0];
  float ga = ldany(gamma, 0, mode);
  float alpha = 1.f / (1.f + __expf(-ga));

  #pragma unroll
  for (int h = 0; h < 2; ++h) {
    __syncthreads();
    if (qh == h) {
      #pragma unroll
      for (int r = 0; r < 16; ++r) {
        int qq = (r & 3) + 8 * (r >> 2) + 4 * lh;
        agPart[mq][qq][lr]      = acc0[r];
        agPart[mq][qq][32 + lr] = acc1[r];
      }
    }
    __syncthreads();
    if (t < 256) {
      int w2 = t >> 6, l2 = t & 63, lr2 = l2 & 31, lh2 = l2 >> 5;
      #pragma unroll
      for (int jj = 0; jj < 8; ++jj) {
        int c = w2 * 16 + lh2 * 8 + jj;
        float vsum = 0.f;
        #pragma unroll
        for (int p = 0; p < 8; ++p) vsum += agPart[p][lr2][c];
        agF[lr2][c] = f2bf(vsum);
      }
    }
    __syncthreads();
    if (qh == h && mq < 4) {
      f32x16 oacc;
      #pragma unroll
      for (int i = 0; i < 16; ++i) oacc[i] = 0.f;
      #pragma unroll
      for (int ks = 0; ks < 4; ++ks) {
        bf16x8 aw = __builtin_bit_cast(bf16x8, wF[(mq * 4 + ks) * 64 + l]);
        bf16x8 bg = __builtin_bit_cast(bf16x8, *(const uint4*)&agF[lr][ks * 16 + lh * 8]);
        oacc = mfma_bf16(aw, bg, oacc);
      }
      if (mode) {
        float* o0 = (float*)out_base;
        float* o1 = o0 + NX;
        const float* xf = (const float*)x;
        #pragma unroll
        for (int r = 0; r < 16; ++r) {
          int o = mq * 32 + (r & 3) + 8 * (r >> 2) + 4 * lh;
          size_t oi = ((size_t)b * CH + o) * NQ + q0 + h * 32 + lr;
          float ag = oacc[r] + bAllf[96 + o];
          o0[oi] = (1.f - alpha) * xf[oi] + alpha * ag;
          o1[oi] = ag;
        }
      } else {
        ushort* o0 = (ushort*)out_base;
        ushort* o1 = o0 + NX;
        const ushort* xu = (const ushort*)x;
        #pragma unroll
        for (int r = 0; r < 16; ++r) {
          int o = mq * 32 + (r & 3) + 8 * (r >> 2) + 4 * lh;
          size_t oi = ((size_t)b * CH + o) * NQ + q0 + h * 32 + lr;
          float ag = oacc[r] + bAllf[96 + o];
          o0[oi] = f2bf((1.f - alpha) * bf2f(xu[oi]) + alpha * ag);
          o1[oi] = f2bf(ag);
        }
      }
    }
  }
}

extern "C" void kernel_launch(void* const* d_in, const int* in_sizes, int n_in,
                              void* d_out, int out_size, void* d_ws, size_t ws_size,
                              hipStream_t stream) {
  const void* x    = d_in[0];
  const void* wT   = d_in[1];
  const void* bT   = d_in[2];
  const void* wP   = d_in[3];
  const void* bP   = d_in[4];
  const void* wG   = d_in[5];
  const void* bG   = d_in[6];
  const void* wAG  = d_in[7];
  const void* bAG  = d_in[8];
  const void* gmm  = d_in[9];

  char* ws = (char*)d_ws;
  ushort* theta  = (ushort*)(ws + 0);          // 1 MB
  ushort* phi    = (ushort*)(ws + 1048576);    // 256 KB
  ushort* gm     = (ushort*)(ws + 1310720);    // 1 MB  [b][m][64] bf16
  float*  part   = (float*) (ws + 2359296);    // 1 MB
  uint4*  gsF    = (uint4*) (ws + 3407872);    // 1 MB  pre-swizzled PV B-frags
  uint4*  wF     = (uint4*) (ws + 4456448);    // 16 KB
  float*  wAllf  = (float*) (ws + 4472832);    // 48 KB
  float*  bAllf  = (float*) (ws + 4521984);    // 1 KB
  int*    flag   = (int*)   (ws + 4523008);    // 4 B
  ushort* xc     = (ushort*)(ws + 4523264);    // 8 MB canonical bf16 x

  k_sniff<<<dim3(1), dim3(64), 0, stream>>>(x, flag);
  k_convert<<<dim3(2048), dim3(256), 0, stream>>>(x, flag, xc);
  k_prep<<<dim3(5), dim3(256), 0, stream>>>(wT, bT, wP, bP, wG, bG, wAG, bAG, flag, wAllf, bAllf, wF);
  k_proj<<<dim3(192, 2), dim3(256), 0, stream>>>(x, xc, flag, wAllf, bAllf, theta, phi, gm);
  k_denom<<<dim3(32, 32, 2), dim3(256), 0, stream>>>(theta, phi, part);
  k_gsf<<<dim3(128, 2), dim3(256), 0, stream>>>(part, gm, gsF);
  k_attn<<<dim3(256, 2), dim3(1024), 0, stream>>>(theta, phi, gsF, wF, bAllf, x, gmm, flag, d_out);
}

// Round 9
// 95.469 us; speedup vs baseline: 1.6795x; 1.6795x over previous
//
#include <hip/hip_runtime.h>

typedef short bf16x8 __attribute__((ext_vector_type(8)));
typedef float f32x16 __attribute__((ext_vector_type(16)));

#define DI __device__ __forceinline__

constexpr int BS = 2, CH = 128;
constexpr int NQ = 16384, NM = 4096;
constexpr size_t NX = (size_t)BS * CH * NQ;   // elements per output tensor

DI float bf2f(ushort u) { unsigned v = ((unsigned)u) << 16; return __builtin_bit_cast(float, v); }
DI ushort f2bf(float f) {
  unsigned u = __builtin_bit_cast(unsigned, f);
  u += 0x7FFFu + ((u >> 16) & 1u);   // RNE
  return (ushort)(u >> 16);
}
DI float ldany(const void* p, size_t i, int f) {
  return f ? ((const float*)p)[i] : bf2f(((const ushort*)p)[i]);
}
DI f32x16 mfma_bf16(bf16x8 a, bf16x8 b, f32x16 c) {
  return __builtin_amdgcn_mfma_f32_32x32x16_bf16(a, b, c, 0, 0, 0);
}
DI float fexp2(float x) { return __builtin_amdgcn_exp2f(x); }   // 1x v_exp_f32

// ---------------- dtype sniff ----------------
__global__ void k_sniff(const void* __restrict__ x, int* __restrict__ flag) {
  if (threadIdx.x == 0 && blockIdx.x == 0) {
    const ushort* u = (const ushort*)x;
    int garbage = 0, zeros = 0;
    for (int i = 0; i < 256; ++i) {
      float v = bf2f(u[i]);
      if (!(fabsf(v) < 1e9f)) garbage++;
      if ((i & 1) == 0 && u[i] == 0) zeros++;
    }
    flag[0] = (garbage >= 8 || zeros >= 100) ? 1 : 0;   // 1 = f32 buffers
  }
}

// ---------------- weight prep ----------------
// bAllf: [0,16) bT, [16,32) bP, [32,96) bG, [96,224) bAG
// wF:  epilogue A-frags of w_attn_g: [ot4][ks4][lane64] -> 8 bf16
// wBf: k_proj B-frags: [kb8][ob3][lane64] -> W[o=ob*32+(l&31)][c=kb*16+(l>>5)*8+j]
//      (rows 0-15 w_theta, 16-31 w_phi, 32-95 w_g)
__global__ __launch_bounds__(256) void k_prep(
    const void* __restrict__ wT, const void* __restrict__ bT,
    const void* __restrict__ wP, const void* __restrict__ bP,
    const void* __restrict__ wG, const void* __restrict__ bG,
    const void* __restrict__ wAG, const void* __restrict__ bAG,
    const int* __restrict__ flag,
    float* __restrict__ bAllf, uint4* __restrict__ wF, uint4* __restrict__ wBf)
{
  int t = threadIdx.x;
  int f = flag[0];
  if (blockIdx.x == 0) {
    if (t < 16)  bAllf[t]       = ldany(bT, t, f);
    if (t < 16)  bAllf[16 + t]  = ldany(bP, t, f);
    if (t < 64)  bAllf[32 + t]  = ldany(bG, t, f);
    if (t < 128) bAllf[96 + t]  = ldany(bAG, t, f);
  } else if (blockIdx.x <= 4) {
    int idx = (blockIdx.x - 1) * 256 + t;  // 0..1023
    int lane = idx & 63, ks = (idx >> 6) & 3, ot = idx >> 8;
    size_t src = (size_t)(ot * 32 + (lane & 31)) * 64 + ks * 16 + (lane >> 5) * 8;
    union { uint4 v4; ushort s[8]; } o;
    #pragma unroll
    for (int j = 0; j < 8; ++j) o.s[j] = f2bf(ldany(wAG, src + j, f));
    wF[idx] = o.v4;
  } else {
    int idx = (int)(blockIdx.x - 5) * 256 + t;  // 0..1535
    int kb = idx / 192, rem = idx % 192;
    int ob = rem >> 6, lane = rem & 63;
    int r = ob * 32 + (lane & 31);
    int c = kb * 16 + (lane >> 5) * 8;
    const void* src; int row;
    if (r < 16)      { src = wT; row = r; }
    else if (r < 32) { src = wP; row = r - 16; }
    else             { src = wG; row = r - 32; }
    union { uint4 v4; ushort s[8]; } o;
    #pragma unroll
    for (int j = 0; j < 8; ++j) o.s[j] = f2bf(ldany(src, (size_t)row * 128 + c + j, f));
    wBf[(kb * 3 + ob) * 64 + lane] = o.v4;
  }
}

// ---------------- projections via MFMA ----------------
// Block: 128 threads = 2 waves, 64 consecutive q (one w-pair). Wave w owns 32 q.
// acc[ob] = sum_kb mfma(A=x^T[q][c] frag, B=wBf[kb][ob]) -> C[32q][32o].
// Epilogue per ob through LDS 64x33 f32 tile: theta (tanh*log2e), phi (2x2 pool
// + tanh), g (2x2 pool, row-major gm[m][64] bf16). Dual-mode x (f32/bf16).
__global__ __launch_bounds__(128) void k_proj(
    const void* __restrict__ x, const int* __restrict__ flag,
    const uint4* __restrict__ wBf, const float* __restrict__ bAllf,
    ushort* __restrict__ theta, ushort* __restrict__ phi, ushort* __restrict__ gm)
{
  int b = blockIdx.y;
  int qt = blockIdx.x;              // 0..255, 64 q each
  int t = threadIdx.x;
  int w = t >> 6, l = t & 63, lr = l & 31, lh = l >> 5;
  int f = flag[0];

  __shared__ float tile[64][33];

  size_t xbase = (size_t)b * CH * NQ + qt * 64 + w * 32 + lr;

  f32x16 acc0, acc1, acc2;
  #pragma unroll
  for (int i = 0; i < 16; ++i) { acc0[i] = 0.f; acc1[i] = 0.f; acc2[i] = 0.f; }

  #pragma unroll
  for (int kb = 0; kb < 8; ++kb) {
    union { uint4 v4; ushort s[8]; } a;
    int cb = kb * 16 + lh * 8;
    if (f) {
      const float* xf = (const float*)x;
      #pragma unroll
      for (int j = 0; j < 8; ++j) a.s[j] = f2bf(xf[xbase + (size_t)(cb + j) * NQ]);
    } else {
      const ushort* xu = (const ushort*)x;
      #pragma unroll
      for (int j = 0; j < 8; ++j) a.s[j] = xu[xbase + (size_t)(cb + j) * NQ];
    }
    bf16x8 aF = __builtin_bit_cast(bf16x8, a.v4);
    uint4 b0 = wBf[(kb * 3 + 0) * 64 + l];
    uint4 b1 = wBf[(kb * 3 + 1) * 64 + l];
    uint4 b2 = wBf[(kb * 3 + 2) * 64 + l];
    acc0 = mfma_bf16(aF, __builtin_bit_cast(bf16x8, b0), acc0);
    acc1 = mfma_bf16(aF, __builtin_bit_cast(bf16x8, b1), acc1);
    acc2 = mfma_bf16(aF, __builtin_bit_cast(bf16x8, b2), acc2);
  }

  constexpr float L2E = 1.4426950408889634f;

  #pragma unroll
  for (int ob = 0; ob < 3; ++ob) {
    __syncthreads();
    {
      f32x16 A = (ob == 0) ? acc0 : ((ob == 1) ? acc1 : acc2);
      #pragma unroll
      for (int r = 0; r < 16; ++r) {
        int qq = (r & 3) + 8 * (r >> 2) + 4 * lh;
        tile[w * 32 + qq][lr] = A[r];
      }
    }
    __syncthreads();
    if (ob == 0) {
      if (t < 64) {                      // theta: row q_local = t
        union { uint4 v4[2]; ushort s[16]; } th;
        #pragma unroll
        for (int c = 0; c < 16; ++c)
          th.s[c] = f2bf(tanhf(tile[t][c] + bAllf[c]) * L2E);
        uint4* dst = (uint4*)(theta + ((size_t)b * NQ + qt * 64 + t) * 16);
        dst[0] = th.v4[0]; dst[1] = th.v4[1];
      } else {                           // phi: 16 m x 16 c, 4 threads/m
        int idx = t - 64;
        int m = idx >> 2, c4 = (idx & 3) * 4;
        int h2 = m * 2;
        union { uint2 v2; ushort s[4]; } ph;
        #pragma unroll
        for (int cc = 0; cc < 4; ++cc) {
          int c = 16 + c4 + cc;
          float z = fmaxf(fmaxf(tile[h2][c], tile[h2 + 1][c]),
                          fmaxf(tile[32 + h2][c], tile[32 + h2 + 1][c]));
          ph.s[cc] = f2bf(tanhf(z + bAllf[c]));
        }
        *(uint2*)(phi + ((size_t)b * NM + qt * 16 + m) * 16 + c4) = ph.v2;
      }
    } else {                             // g: 16 m x 32 c, 8 threads/m
      int cb = (ob - 1) * 32;
      int m = t >> 3, c4 = (t & 7) * 4;
      int h2 = m * 2;
      union { uint2 v2; ushort s[4]; } gv;
      #pragma unroll
      for (int cc = 0; cc < 4; ++cc) {
        int c = c4 + cc;
        float z = fmaxf(fmaxf(tile[h2][c], tile[h2 + 1][c]),
                        fmaxf(tile[32 + h2][c], tile[32 + h2 + 1][c]));
        gv.s[cc] = f2bf(z + bAllf[32 + cb + c]);
      }
      *(uint2*)(gm + ((size_t)b * NM + qt * 16 + m) * 64 + cb + c4) = gv.v2;
    }
  }
}

// ---------------- softmax denominator partials ----------------
__global__ __launch_bounds__(256, 8) void k_denom(
    const ushort* __restrict__ theta, const ushort* __restrict__ phi,
    float* __restrict__ partial)
{
  int b = blockIdx.z, qs = blockIdx.y;
  int w = threadIdx.x >> 6;
  int l = threadIdx.x & 63, lr = l & 31, lh = l >> 5;
  int m0 = blockIdx.x * 128 + w * 32;

  bf16x8 pB = __builtin_bit_cast(bf16x8, *(const uint4*)(phi + ((size_t)b * NM + m0 + lr) * 16 + lh * 8));

  float s = 0.f;
  int qb = qs * 512;
  for (int qq = 0; qq < 512; qq += 32) {
    bf16x8 tA = __builtin_bit_cast(bf16x8, *(const uint4*)(theta + ((size_t)b * NQ + qb + qq + lr) * 16 + lh * 8));
    f32x16 S;
    #pragma unroll
    for (int i = 0; i < 16; ++i) S[i] = 0.f;
    S = mfma_bf16(tA, pB, S);
    #pragma unroll
    for (int r = 0; r < 16; ++r) s += fexp2(S[r]);
  }
  s += __shfl_xor(s, 32, 64);
  if (l < 32) partial[(((size_t)b * 32 + qs) << 12) + m0 + lr] = s;
}

// ---------------- dinv reduce + scale + PV B-frag pack ----------------
__global__ __launch_bounds__(256) void k_gsf(
    const float* __restrict__ partial, const ushort* __restrict__ gm,
    uint4* __restrict__ gsF)
{
  int b = blockIdx.y, mb = blockIdx.x;   // 128 chunks of 32 m
  int t = threadIdx.x;
  int mbase = mb * 32;

  __shared__ float dinv_sh[32];
  __shared__ float tile[32][65];

  if (t < 32) {
    int m = mbase + t;
    float s = 0.f;
    #pragma unroll
    for (int p = 0; p < 32; ++p) s += partial[(((size_t)b * 32 + p) << 12) + m];
    dinv_sh[t] = 1.f / s;
  }
  __syncthreads();

  {
    int m_loc = t >> 3, c = (t & 7) * 8;
    union { uint4 v4; ushort s[8]; } v;
    v.v4 = *(const uint4*)(gm + ((size_t)b * NM + mbase + m_loc) * 64 + c);
    float dv = dinv_sh[m_loc];
    #pragma unroll
    for (int j = 0; j < 8; ++j) tile[m_loc][c + j] = bf2f(v.s[j]) * dv;
  }
  __syncthreads();

  int ms_loc = t >> 7, ct = (t >> 6) & 1, lane = t & 63;
  int col = ct * 32 + (lane & 31);
  int rbase = ms_loc * 16 + (lane >> 5) * 8;
  union { uint4 v4; ushort s[8]; } o;
  #pragma unroll
  for (int j = 0; j < 8; ++j) o.s[j] = f2bf(tile[rbase + j][col]);
  int ms = (mbase >> 4) + ms_loc;
  gsF[(((size_t)b * 256 + ms) * 2 + ct) * 64 + lane] = o.v4;
}

// ---------------- fused attention + output ----------------
__global__ __launch_bounds__(1024, 4) void k_attn(
    const ushort* __restrict__ theta, const ushort* __restrict__ phi,
    const uint4* __restrict__ gsF, const uint4* __restrict__ wF,
    const float* __restrict__ bAllf, const void* __restrict__ x,
    const void* __restrict__ gamma, const int* __restrict__ flag,
    void* __restrict__ out_base)
{
  int b = blockIdx.y;
  int q0 = blockIdx.x * 64;
  int t = threadIdx.x;
  int w = t >> 6, l = t & 63, lr = l & 31, lh = l >> 5;
  int mq = w & 7, qh = w >> 3;

  __shared__ float agPart[8][32][65];
  __shared__ __align__(16) ushort agF[32][80];

  int qw = q0 + qh * 32;
  bf16x8 tB = __builtin_bit_cast(bf16x8, *(const uint4*)(theta + ((size_t)b * NQ + qw + lr) * 16 + lh * 8));

  const ushort* phb = phi + ((size_t)b * NM + lr) * 16 + lh * 8;
  const uint4* gF = gsF + (size_t)b * 256 * 128;

  f32x16 acc0, acc1;
  #pragma unroll
  for (int i = 0; i < 16; ++i) { acc0[i] = 0.f; acc1[i] = 0.f; }

  int m0 = mq * 32;
  int ms0 = m0 >> 4;
  bf16x8 pA = __builtin_bit_cast(bf16x8, *(const uint4*)(phb + (size_t)m0 * 16));
  uint4 g00 = gF[ms0 * 128 + l];
  uint4 g01 = gF[ms0 * 128 + 64 + l];
  uint4 g10 = gF[ms0 * 128 + 128 + l];
  uint4 g11 = gF[ms0 * 128 + 192 + l];

  for (int it = 0; it < 16; ++it) {
    int mn = mq * 32 + ((it + 1) & 15) * 256;
    int msn = mn >> 4;
    bf16x8 pAn = __builtin_bit_cast(bf16x8, *(const uint4*)(phb + (size_t)mn * 16));
    uint4 n00 = gF[msn * 128 + l];
    uint4 n01 = gF[msn * 128 + 64 + l];
    uint4 n10 = gF[msn * 128 + 128 + l];
    uint4 n11 = gF[msn * 128 + 192 + l];
    __builtin_amdgcn_sched_barrier(0);

    f32x16 S;
    #pragma unroll
    for (int i = 0; i < 16; ++i) S[i] = 0.f;
    S = mfma_bf16(pA, tB, S);

    #pragma unroll
    for (int r = 0; r < 16; ++r) S[r] = fexp2(S[r]);

    uint u0, u1, u2, u3, u4, u5, u6, u7;
    asm("v_cvt_pk_bf16_f32 %0, %1, %2" : "=v"(u0) : "v"(S[0]),  "v"(S[1]));
    asm("v_cvt_pk_bf16_f32 %0, %1, %2" : "=v"(u1) : "v"(S[2]),  "v"(S[3]));
    asm("v_cvt_pk_bf16_f32 %0, %1, %2" : "=v"(u2) : "v"(S[4]),  "v"(S[5]));
    asm("v_cvt_pk_bf16_f32 %0, %1, %2" : "=v"(u3) : "v"(S[6]),  "v"(S[7]));
    asm("v_cvt_pk_bf16_f32 %0, %1, %2" : "=v"(u4) : "v"(S[8]),  "v"(S[9]));
    asm("v_cvt_pk_bf16_f32 %0, %1, %2" : "=v"(u5) : "v"(S[10]), "v"(S[11]));
    asm("v_cvt_pk_bf16_f32 %0, %1, %2" : "=v"(u6) : "v"(S[12]), "v"(S[13]));
    asm("v_cvt_pk_bf16_f32 %0, %1, %2" : "=v"(u7) : "v"(S[14]), "v"(S[15]));

    asm("v_permlane32_swap_b32 %0, %1" : "+v"(u0), "+v"(u2));
    asm("v_permlane32_swap_b32 %0, %1" : "+v"(u1), "+v"(u3));
    asm("v_permlane32_swap_b32 %0, %1" : "+v"(u4), "+v"(u6));
    asm("v_permlane32_swap_b32 %0, %1" : "+v"(u5), "+v"(u7));

    uint4 fa0 = make_uint4(u0, u1, u2, u3);
    uint4 fa1 = make_uint4(u4, u5, u6, u7);

    acc0 = mfma_bf16(__builtin_bit_cast(bf16x8, fa0), __builtin_bit_cast(bf16x8, g00), acc0);
    acc1 = mfma_bf16(__builtin_bit_cast(bf16x8, fa0), __builtin_bit_cast(bf16x8, g01), acc1);
    acc0 = mfma_bf16(__builtin_bit_cast(bf16x8, fa1), __builtin_bit_cast(bf16x8, g10), acc0);
    acc1 = mfma_bf16(__builtin_bit_cast(bf16x8, fa1), __builtin_bit_cast(bf16x8, g11), acc1);

    pA = pAn; g00 = n00; g01 = n01; g10 = n10; g11 = n11;
  }

  int mode = flag[0];
  float ga = ldany(gamma, 0, mode);
  float alpha = 1.f / (1.f + __expf(-ga));

  #pragma unroll
  for (int h = 0; h < 2; ++h) {
    __syncthreads();
    if (qh == h) {
      #pragma unroll
      for (int r = 0; r < 16; ++r) {
        int qq = (r & 3) + 8 * (r >> 2) + 4 * lh;
        agPart[mq][qq][lr]      = acc0[r];
        agPart[mq][qq][32 + lr] = acc1[r];
      }
    }
    __syncthreads();
    if (t < 256) {
      int w2 = t >> 6, l2 = t & 63, lr2 = l2 & 31, lh2 = l2 >> 5;
      #pragma unroll
      for (int jj = 0; jj < 8; ++jj) {
        int c = w2 * 16 + lh2 * 8 + jj;
        float vsum = 0.f;
        #pragma unroll
        for (int p = 0; p < 8; ++p) vsum += agPart[p][lr2][c];
        agF[lr2][c] = f2bf(vsum);
      }
    }
    __syncthreads();
    if (qh == h && mq < 4) {
      f32x16 oacc;
      #pragma unroll
      for (int i = 0; i < 16; ++i) oacc[i] = 0.f;
      #pragma unroll
      for (int ks = 0; ks < 4; ++ks) {
        bf16x8 aw = __builtin_bit_cast(bf16x8, wF[(mq * 4 + ks) * 64 + l]);
        bf16x8 bg = __builtin_bit_cast(bf16x8, *(const uint4*)&agF[lr][ks * 16 + lh * 8]);
        oacc = mfma_bf16(aw, bg, oacc);
      }
      if (mode) {
        float* o0 = (float*)out_base;
        float* o1 = o0 + NX;
        const float* xf = (const float*)x;
        #pragma unroll
        for (int r = 0; r < 16; ++r) {
          int o = mq * 32 + (r & 3) + 8 * (r >> 2) + 4 * lh;
          size_t oi = ((size_t)b * CH + o) * NQ + q0 + h * 32 + lr;
          float ag = oacc[r] + bAllf[96 + o];
          o0[oi] = (1.f - alpha) * xf[oi] + alpha * ag;
          o1[oi] = ag;
        }
      } else {
        ushort* o0 = (ushort*)out_base;
        ushort* o1 = o0 + NX;
        const ushort* xu = (const ushort*)x;
        #pragma unroll
        for (int r = 0; r < 16; ++r) {
          int o = mq * 32 + (r & 3) + 8 * (r >> 2) + 4 * lh;
          size_t oi = ((size_t)b * CH + o) * NQ + q0 + h * 32 + lr;
          float ag = oacc[r] + bAllf[96 + o];
          o0[oi] = f2bf((1.f - alpha) * bf2f(xu[oi]) + alpha * ag);
          o1[oi] = f2bf(ag);
        }
      }
    }
  }
}

extern "C" void kernel_launch(void* const* d_in, const int* in_sizes, int n_in,
                              void* d_out, int out_size, void* d_ws, size_t ws_size,
                              hipStream_t stream) {
  const void* x    = d_in[0];
  const void* wT   = d_in[1];
  const void* bT   = d_in[2];
  const void* wP   = d_in[3];
  const void* bP   = d_in[4];
  const void* wG   = d_in[5];
  const void* bG   = d_in[6];
  const void* wAG  = d_in[7];
  const void* bAG  = d_in[8];
  const void* gmm  = d_in[9];

  char* ws = (char*)d_ws;
  ushort* theta  = (ushort*)(ws + 0);          // 1 MB
  ushort* phi    = (ushort*)(ws + 1048576);    // 256 KB
  ushort* gm     = (ushort*)(ws + 1310720);    // 1 MB  [b][m][64] bf16
  float*  part   = (float*) (ws + 2359296);    // 1 MB
  uint4*  gsF    = (uint4*) (ws + 3407872);    // 1 MB  pre-swizzled PV B-frags
  uint4*  wF     = (uint4*) (ws + 4456448);    // 16 KB
  uint4*  wBf    = (uint4*) (ws + 4472832);    // 24 KB k_proj B-frags
  float*  bAllf  = (float*) (ws + 4497408);    // 1 KB
  int*    flag   = (int*)   (ws + 4498432);    // 4 B

  k_sniff<<<dim3(1), dim3(64), 0, stream>>>(x, flag);
  k_prep<<<dim3(11), dim3(256), 0, stream>>>(wT, bT, wP, bP, wG, bG, wAG, bAG, flag, bAllf, wF, wBf);
  k_proj<<<dim3(256, 2), dim3(128), 0, stream>>>(x, flag, wBf, bAllf, theta, phi, gm);
  k_denom<<<dim3(32, 32, 2), dim3(256), 0, stream>>>(theta, phi, part);
  k_gsf<<<dim3(128, 2), dim3(256), 0, stream>>>(part, gm, gsF);
  k_attn<<<dim3(256, 2), dim3(1024), 0, stream>>>(theta, phi, gsF, wF, bAllf, x, gmm, flag, d_out);
}